// Round 11
// baseline (7027.895 us; speedup 1.0000x reference)
//
#include <hip/hip_runtime.h>
#include <hip/hip_bf16.h>

#pragma clang fp contract(off)

#define NTH   512       // 8 waves; one block per CU (only 16 blocks chip-wide)
#define PPT   32        // NTH*PPT == NPTS
#define NPTS  16384
#define BATCH 16
#define CFEAT 128
#define SMAX  4096
#define NWAVE (NTH / 64)

// Pin into a VGPR (opaque to optimizer: no rematerialization from memory).
__device__ __forceinline__ float f32_pin(float x) {
    asm volatile("" : "+v"(x));
    return x;
}

// ---------------------------------------------------------------------------
// FPS kernel, one block per batch.
// CORRECTNESS INVARIANTS (proven r0-r10; do not change):
//   * d  = fma(dz,dz, fma(dx,dx, dy*dy))      [XLA contraction form]
//   * md = fminf(D[k], d)
//   * argmax: max value, ties -> LOWEST original point index
//   * emission: idx[t] = last BEFORE the update pass
// r11 machinery:
//   * launch_bounds(512,1): only 16 blocks exist -> 1 block/CU regardless, so
//     occupancy beyond 8 waves is worthless; give the allocator ~256 arch
//     VGPRs so X/Y/Z/D (128 floats) stay in real VGPRs (r10's VGPR=76 showed
//     AGPR-parking: ~5 v_accvgpr moves/point ≈ +1300 cyc/iter).
//   * contiguous mapping gi = tid*32+k (lexicographic by (lane,k)) -> value-
//     only inner loop; index recovered on candidate waves only.
//   * wave-representative broadcast: candidate wave's lowest candidate lane
//     rescans with STATIC unroll (cndmask selects, no runtime reg indexing)
//     and publishes {gi,x,y,z} to per-wave LDS; min-gi slot wins. No atomics,
//     no global coord fetch, 2 barriers/iter.
// ---------------------------------------------------------------------------
template <bool FUSED>
__global__ __launch_bounds__(NTH, 1) void fps_kernel(const float* __restrict__ xyz,
                                                     const float* __restrict__ x,
                                                     int* __restrict__ idx_out,
                                                     float* __restrict__ out,
                                                     int S) {
    const int b    = blockIdx.x;
    const int tid  = threadIdx.x;
    const int wid  = tid >> 6;
    const int lane = tid & 63;
    const float* __restrict__ xb = xyz + (size_t)b * 3 * NPTS;

    float X[PPT], Y[PPT], Z[PPT], D[PPT];
    const int p0 = tid * PPT;
#pragma unroll
    for (int k = 0; k < PPT; ++k) {
        X[k] = f32_pin(xb[p0 + k]);
        Y[k] = f32_pin(xb[NPTS + p0 + k]);
        Z[k] = f32_pin(xb[2 * NPTS + p0 + k]);
        D[k] = INFINITY;
    }

    __shared__ unsigned s_vmax[NWAVE];
    __shared__ unsigned s_cgi[NWAVE];
    __shared__ float    s_cx[NWAVE], s_cy[NWAVE], s_cz[NWAVE];
    __shared__ int      s_idx[FUSED ? SMAX : 1];

    int   last = 0;
    float px = xb[0], py = xb[NPTS], pz = xb[2 * NPTS];

    for (int t = 0; t < S; ++t) {
        if (tid == 0) {
            if (FUSED) s_idx[t] = last;
            else       idx_out[b * S + t] = last;
        }

        // ---- update pass: value-only, 8 VALU/pt, registers only
        float best = -INFINITY;
#pragma unroll
        for (int k = 0; k < PPT; ++k) {
            const float dx = X[k] - px;
            const float dy = Y[k] - py;
            const float dz = Z[k] - pz;
            const float d  = __builtin_fmaf(dz, dz,
                               __builtin_fmaf(dx, dx, dy * dy));
            const float md = fminf(D[k], d);
            D[k] = md;
            best = fmaxf(best, md);
        }
        const unsigned mybits = __float_as_uint(best);  // d>=0: uint order == float order

        // ---- wave max: u32 butterfly
        unsigned bu = mybits;
#pragma unroll
        for (int off = 32; off >= 1; off >>= 1) {
            const unsigned o = __shfl_xor(bu, off);
            bu = (o > bu) ? o : bu;
        }
        if (lane == 0) s_vmax[wid] = bu;
        __syncthreads();                               // B1

        // ---- block max (broadcast LDS reads)
        unsigned vb = s_vmax[0];
#pragma unroll
        for (int w = 1; w < NWAVE; ++w) {
            const unsigned vw = s_vmax[w];
            vb = (vw > vb) ? vw : vb;
        }

        // ---- candidate waves publish {gi, coords} via representative lane
        if (lane == 0) s_cgi[wid] = 0xFFFFFFFFu;       // same-wave order: may be
        if (bu == vb) {                                //   overwritten below
            const unsigned long long m = __ballot(mybits == vb);
            const int rep = (int)__ffsll((long long)m) - 1;  // lowest lane => lowest gi
            if (lane == rep) {
                unsigned cg = 0xFFFFFFFFu;
                float cx = 0.f, cy = 0.f, cz = 0.f;
#pragma unroll
                for (int k = PPT - 1; k >= 0; --k) {   // ends at LOWEST matching k
                    if (__float_as_uint(D[k]) == vb) {
                        cg = (unsigned)(p0 + k);
                        cx = X[k]; cy = Y[k]; cz = Z[k];
                    }
                }
                s_cgi[wid] = cg;
                s_cx[wid] = cx; s_cy[wid] = cy; s_cz[wid] = cz;
            }
        }
        __syncthreads();                               // B2

        // ---- winner = min gi across wave slots; coords from its slot
        unsigned g = s_cgi[0];
        int      w = 0;
#pragma unroll
        for (int w2 = 1; w2 < NWAVE; ++w2) {
            const unsigned g2 = s_cgi[w2];
            if (g2 < g) { g = g2; w = w2; }
        }
        last = (int)g;
        px = s_cx[w]; py = s_cy[w]; pz = s_cz[w];
    }

    if (FUSED) {
        __syncthreads();
        for (int i = tid; i < CFEAT * S; i += NTH) {
            const int c = i / S, s = i - c * S;
            const long r = (long)b * CFEAT + c;
            out[r * S + s] = x[r * NPTS + s_idx[s]];
        }
        const long base = (long)BATCH * CFEAT * S;
        for (int i = tid; i < 3 * S; i += NTH) {
            const int c = i / S, s = i - c * S;
            const long r = (long)b * 3 + c;
            out[base + r * S + s] = xyz[r * NPTS + s_idx[s]];
        }
    }
}

// ---------------------------------------------------------------------------
// Gather kernel (full-chip): out = concat( x_s [B][C][S], xyz_s [B][3][S] ).
// ---------------------------------------------------------------------------
__global__ void gather_kernel(const float* __restrict__ x,
                              const float* __restrict__ xyz,
                              const int* __restrict__ idx,
                              float* __restrict__ out,
                              int S) {
    const long nxs   = (long)BATCH * CFEAT * S;
    const long total = nxs + (long)BATCH * 3 * S;
    for (long i = (long)blockIdx.x * blockDim.x + threadIdx.x; i < total;
         i += (long)gridDim.x * blockDim.x) {
        if (i < nxs) {
            const int s  = (int)(i % S);
            const long r = i / S;            // b*C + c
            const int b  = (int)(r / CFEAT);
            const int p  = idx[b * S + s];
            out[i] = x[r * NPTS + p];
        } else {
            const long j = i - nxs;
            const int s  = (int)(j % S);
            const long r = j / S;            // b*3 + c
            const int b  = (int)(r / 3);
            const int p  = idx[b * S + s];
            out[i] = xyz[r * NPTS + p];
        }
    }
}

extern "C" void kernel_launch(void* const* d_in, const int* in_sizes, int n_in,
                              void* d_out, int out_size, void* d_ws, size_t ws_size,
                              hipStream_t stream) {
    const float* x   = nullptr;   // [B, C, N]
    const float* xyz = nullptr;   // [B, 3, N]
    for (int i = 0; i < n_in; ++i) {
        if (in_sizes[i] == BATCH * CFEAT * NPTS)  x   = (const float*)d_in[i];
        else if (in_sizes[i] == BATCH * 3 * NPTS) xyz = (const float*)d_in[i];
    }
    float* out = (float*)d_out;
    const int S = out_size / (BATCH * (CFEAT + 3));

    const size_t need = (size_t)BATCH * (size_t)S * sizeof(int);
    if (ws_size >= need && d_ws != nullptr) {
        int* idx = (int*)d_ws;
        fps_kernel<false><<<BATCH, NTH, 0, stream>>>(xyz, nullptr, idx, nullptr, S);
        gather_kernel<<<2048, 256, 0, stream>>>(x, xyz, idx, out, S);
    } else {
        fps_kernel<true><<<BATCH, NTH, 0, stream>>>(xyz, x, nullptr, out, S);
    }
}

// Round 12
// 5566.459 us; speedup vs baseline: 1.2625x; 1.2625x over previous
//
#include <hip/hip_runtime.h>
#include <hip/hip_bf16.h>

#pragma clang fp contract(off)

#define NTH   1024      // 16 waves = exactly 1 block/CU at 4 waves/EU
#define PPT   16        // NTH*PPT == NPTS; 64 floats state/thread fits 128-VGPR cap
#define NPTS  16384
#define BATCH 16
#define CFEAT 128
#define SMAX  4096
#define NWAVE (NTH / 64)

// Pin into a VGPR (opaque to optimizer: no rematerialization from memory).
__device__ __forceinline__ float f32_pin(float x) {
    asm volatile("" : "+v"(x));
    return x;
}

// ---------------------------------------------------------------------------
// FPS kernel, one block per batch.
// CORRECTNESS INVARIANTS (proven r0-r11; do not change):
//   * d  = fma(dz,dz, fma(dx,dx, dy*dy))      [XLA contraction form]
//   * md = fminf(D[k], d)
//   * argmax: max value, ties -> LOWEST original point index
//   * emission: idx[t] = last BEFORE the update pass
// r12 machinery:
//   * NTH=1024/PPT=16 + launch_bounds(1024,4): VGPR cap = 512/4 = 128/wave;
//     state = 64 floats + ~35 temps fits ARCH VGPRs. r10/r11 (NTH=512,PPT=32,
//     128-float state) proved the allocator AGPR-parks beyond ~84 arch VGPRs
//     regardless of launch_bounds -> ~5 v_accvgpr moves/point dominated issue.
//     Fix is to fit the budget, not to fight the allocator.
//   * contiguous mapping gi = tid*16+k (lexicographic by (tid,k)) -> value-
//     only inner loop; index recovered on candidate lanes only (r10 scheme:
//     static-unrolled rescan + atomicMin into rotating 4-slot LDS cell).
//   * winner coords: uniform global fetch (L2-resident), 2 barriers/iter.
// ---------------------------------------------------------------------------
template <bool FUSED>
__global__ __launch_bounds__(NTH, 4) void fps_kernel(const float* __restrict__ xyz,
                                                     const float* __restrict__ x,
                                                     int* __restrict__ idx_out,
                                                     float* __restrict__ out,
                                                     int S) {
    const int b    = blockIdx.x;
    const int tid  = threadIdx.x;
    const int wid  = tid >> 6;
    const int lane = tid & 63;
    const float* __restrict__ xb = xyz + (size_t)b * 3 * NPTS;

    float X[PPT], Y[PPT], Z[PPT], D[PPT];
    const int p0 = tid * PPT;
#pragma unroll
    for (int k = 0; k < PPT; ++k) {
        X[k] = f32_pin(xb[p0 + k]);
        Y[k] = f32_pin(xb[NPTS + p0 + k]);
        Z[k] = f32_pin(xb[2 * NPTS + p0 + k]);
        D[k] = INFINITY;
    }

    __shared__ unsigned s_vmax[NWAVE];
    __shared__ unsigned s_gi[4];
    __shared__ int      s_idx[FUSED ? SMAX : 1];

    if (tid == 0) { s_gi[0] = s_gi[1] = s_gi[2] = s_gi[3] = 0xFFFFFFFFu; }
    __syncthreads();

    int   last = 0;
    float px = xb[0], py = xb[NPTS], pz = xb[2 * NPTS];

    for (int t = 0; t < S; ++t) {
        if (tid == 0) {
            if (FUSED) s_idx[t] = last;
            else       idx_out[b * S + t] = last;
        }

        // ---- update pass: value-only, 8 VALU/pt, arch registers only
        float best = -INFINITY;
#pragma unroll
        for (int k = 0; k < PPT; ++k) {
            const float dx = X[k] - px;
            const float dy = Y[k] - py;
            const float dz = Z[k] - pz;
            const float d  = __builtin_fmaf(dz, dz,
                               __builtin_fmaf(dx, dx, dy * dy));
            const float md = fminf(D[k], d);
            D[k] = md;
            best = fmaxf(best, md);
        }
        const unsigned mybits = __float_as_uint(best);  // d>=0: uint order == float order

        // ---- wave max: u32 butterfly (6 shuffles)
        unsigned bu = mybits;
#pragma unroll
        for (int off = 32; off >= 1; off >>= 1) {
            const unsigned o = __shfl_xor(bu, off);
            bu = (o > bu) ? o : bu;
        }
        if (lane == 0) s_vmax[wid] = bu;
        if (tid == 0)  s_gi[(t + 2) & 3] = 0xFFFFFFFFu;   // rotate-init future slot
        __syncthreads();                                   // B1

        // ---- block max (broadcast LDS reads)
        unsigned vb = s_vmax[0];
#pragma unroll
        for (int w = 1; w < NWAVE; ++w) {
            const unsigned vw = s_vmax[w];
            vb = (vw > vb) ? vw : vb;
        }

        // ---- index resolve: only candidate lanes (~1-2 per block) pay
        if (mybits == vb) {
            int kk = PPT - 1;
#pragma unroll
            for (int k = PPT - 1; k >= 0; --k)
                if (__float_as_uint(D[k]) == mybits) kk = k;   // ends at lowest k
            atomicMin(&s_gi[t & 3], (unsigned)(p0 + kk));
        }
        __syncthreads();                                   // B2

        last = (int)s_gi[t & 3];
        // uniform fetch of the new pick's coordinates (L2-resident)
        px = xb[last];
        py = xb[NPTS + last];
        pz = xb[2 * NPTS + last];
    }

    if (FUSED) {
        __syncthreads();
        for (int i = tid; i < CFEAT * S; i += NTH) {
            const int c = i / S, s = i - c * S;
            const long r = (long)b * CFEAT + c;
            out[r * S + s] = x[r * NPTS + s_idx[s]];
        }
        const long base = (long)BATCH * CFEAT * S;
        for (int i = tid; i < 3 * S; i += NTH) {
            const int c = i / S, s = i - c * S;
            const long r = (long)b * 3 + c;
            out[base + r * S + s] = xyz[r * NPTS + s_idx[s]];
        }
    }
}

// ---------------------------------------------------------------------------
// Gather kernel (full-chip): out = concat( x_s [B][C][S], xyz_s [B][3][S] ).
// ---------------------------------------------------------------------------
__global__ void gather_kernel(const float* __restrict__ x,
                              const float* __restrict__ xyz,
                              const int* __restrict__ idx,
                              float* __restrict__ out,
                              int S) {
    const long nxs   = (long)BATCH * CFEAT * S;
    const long total = nxs + (long)BATCH * 3 * S;
    for (long i = (long)blockIdx.x * blockDim.x + threadIdx.x; i < total;
         i += (long)gridDim.x * blockDim.x) {
        if (i < nxs) {
            const int s  = (int)(i % S);
            const long r = i / S;            // b*C + c
            const int b  = (int)(r / CFEAT);
            const int p  = idx[b * S + s];
            out[i] = x[r * NPTS + p];
        } else {
            const long j = i - nxs;
            const int s  = (int)(j % S);
            const long r = j / S;            // b*3 + c
            const int b  = (int)(r / 3);
            const int p  = idx[b * S + s];
            out[i] = xyz[r * NPTS + p];
        }
    }
}

extern "C" void kernel_launch(void* const* d_in, const int* in_sizes, int n_in,
                              void* d_out, int out_size, void* d_ws, size_t ws_size,
                              hipStream_t stream) {
    const float* x   = nullptr;   // [B, C, N]
    const float* xyz = nullptr;   // [B, 3, N]
    for (int i = 0; i < n_in; ++i) {
        if (in_sizes[i] == BATCH * CFEAT * NPTS)  x   = (const float*)d_in[i];
        else if (in_sizes[i] == BATCH * 3 * NPTS) xyz = (const float*)d_in[i];
    }
    float* out = (float*)d_out;
    const int S = out_size / (BATCH * (CFEAT + 3));

    const size_t need = (size_t)BATCH * (size_t)S * sizeof(int);
    if (ws_size >= need && d_ws != nullptr) {
        int* idx = (int*)d_ws;
        fps_kernel<false><<<BATCH, NTH, 0, stream>>>(xyz, nullptr, idx, nullptr, S);
        gather_kernel<<<2048, 256, 0, stream>>>(x, xyz, idx, out, S);
    } else {
        fps_kernel<true><<<BATCH, NTH, 0, stream>>>(xyz, x, nullptr, out, S);
    }
}